// Round 1
// baseline (649.239 us; speedup 1.0000x reference)
//
#include <hip/hip_runtime.h>
#include <hip/hip_bf16.h>

typedef __bf16 bf16_t;
typedef bf16_t bf16x8 __attribute__((ext_vector_type(8)));
typedef bf16_t bf16x4 __attribute__((ext_vector_type(4)));
typedef float  f32x4  __attribute__((ext_vector_type(4)));

constexpr int BATCH = 16, S = 2048, D = 256;
constexpr int M = BATCH * S; // 32768 token rows

// ---------------- ws layout (bytes) ----------------
// wt     : [3][256][256] bf16  (wt[w][n][k] = W_w[k][n])   @ 0        (393216)
// q      : [B][S][D] bf16                                   @ 393216   (16777216)
// k      : [B][S][D] bf16                                   @ 17170432 (16777216)
// vt     : [B][D][S] bf16  (transposed V)                   @ 33947648 (16777216)
// partial: [B*32][256] f32                                  @ 50724864 (524288)
// total  : 51249152 bytes (~51.3 MB)

// Kernel 1: transpose + convert weights to bf16. 3*256*256 elements.
__global__ void wt_kernel(const float* __restrict__ Wq, const float* __restrict__ Wk,
                          const float* __restrict__ Wv, bf16_t* __restrict__ wt) {
    int idx = blockIdx.x * 256 + threadIdx.x;      // [0, 196608)
    int w = idx >> 16;
    int r = idx & 65535;
    int n = r >> 8;        // output row (dout)
    int kd = r & 255;      // output col (din)
    const float* Wsrc = (w == 0) ? Wq : (w == 1) ? Wk : Wv;
    wt[idx] = (bf16_t)Wsrc[kd * 256 + n];
}

// Kernel 2: QKV projection GEMM. grid (512, 3), 256 threads (4 waves).
// Each wave: 16 token rows x all 256 output cols. x fp32 converted in-register.
__global__ __launch_bounds__(256) void proj_kernel(
    const float* __restrict__ x, const bf16_t* __restrict__ wt,
    const float* __restrict__ bq, const float* __restrict__ bk, const float* __restrict__ bv,
    bf16_t* __restrict__ q, bf16_t* __restrict__ kmat, bf16_t* __restrict__ vt) {
    int w    = blockIdx.y;
    int wave = threadIdx.x >> 6;
    int lane = threadIdx.x & 63;
    int lm   = lane & 15;   // A: row within 16 / B: col within 16
    int lg   = lane >> 4;   // k-group (times 8)
    int m0   = blockIdx.x * 64 + wave * 16;

    const bf16_t* wptr = wt + w * 65536;
    const float*  bias = (w == 0) ? bq : (w == 1) ? bk : bv;

    f32x4 acc[16];
#pragma unroll
    for (int i = 0; i < 16; i++) acc[i] = f32x4{0.f, 0.f, 0.f, 0.f};

    const float* arow = x + (size_t)(m0 + lm) * D + lg * 8;
#pragma unroll
    for (int ks = 0; ks < 8; ks++) {
        float4 f0 = *(const float4*)(arow + ks * 32);
        float4 f1 = *(const float4*)(arow + ks * 32 + 4);
        bf16x8 a;
        a[0] = (bf16_t)f0.x; a[1] = (bf16_t)f0.y; a[2] = (bf16_t)f0.z; a[3] = (bf16_t)f0.w;
        a[4] = (bf16_t)f1.x; a[5] = (bf16_t)f1.y; a[6] = (bf16_t)f1.z; a[7] = (bf16_t)f1.w;
#pragma unroll
        for (int nt = 0; nt < 16; nt++) {
            bf16x8 b = *(const bf16x8*)(wptr + (nt * 16 + lm) * D + ks * 32 + lg * 8);
            acc[nt] = __builtin_amdgcn_mfma_f32_16x16x32_bf16(a, b, acc[nt], 0, 0, 0);
        }
    }

    // Epilogue. C layout: row = lg*4 + r, col = nt*16 + lm.
    int row0 = m0 + lg * 4;
    int bb   = row0 / S;
    int ss   = row0 % S;
#pragma unroll
    for (int nt = 0; nt < 16; nt++) {
        int col = nt * 16 + lm;
        float bval = bias[col];
        if (w == 2) {
            bf16x4 pk;
#pragma unroll
            for (int r = 0; r < 4; r++) pk[r] = (bf16_t)(acc[nt][r] + bval);
            *(bf16x4*)(vt + (size_t)bb * D * S + (size_t)col * S + ss) = pk;
        } else {
            bf16_t* dst = (w == 0) ? q : kmat;
#pragma unroll
            for (int r = 0; r < 4; r++)
                dst[(size_t)(row0 + r) * D + col] = (bf16_t)(acc[nt][r] + bval);
        }
    }
}

// Kernel 3: flash attention + per-block query-sum. grid 512 (= B*32), 256 threads.
__global__ __launch_bounds__(256) void attn_kernel(
    const bf16_t* __restrict__ q, const bf16_t* __restrict__ kmat,
    const bf16_t* __restrict__ vt, float* __restrict__ partial) {
    __shared__ float lds_p[4][16 * 36];   // per-wave P transpose buffer
    __shared__ float psum[4][256];

    int wave = threadIdx.x >> 6;
    int lane = threadIdx.x & 63;
    int lm   = lane & 15;
    int lg   = lane >> 4;
    int b    = blockIdx.x >> 5;
    int qt   = blockIdx.x & 31;
    int q0   = qt * 64 + wave * 16;       // first q row (within batch) for this wave

    // Hoist Q A-frags: 8 frags cover K(d)=256.
    const bf16_t* qbase = q + ((size_t)b * S + q0 + lm) * D + lg * 8;
    bf16x8 afrag[8];
#pragma unroll
    for (int ks = 0; ks < 8; ks++) afrag[ks] = *(const bf16x8*)(qbase + ks * 32);

    f32x4 o_acc[16];
#pragma unroll
    for (int i = 0; i < 16; i++) o_acc[i] = f32x4{0.f, 0.f, 0.f, 0.f};
    float m_run[4], l_run[4];
#pragma unroll
    for (int r = 0; r < 4; r++) { m_run[r] = -1e30f; l_run[r] = 0.f; }

    const bf16_t* kbb = kmat + (size_t)b * S * D;
    const bf16_t* vbb = vt + (size_t)b * D * S;
    float* myp = &lds_p[wave][0];
    constexpr float SCL = 0.0625f * 1.44269504f;  // 1/sqrt(D) folded into log2 domain

    for (int kt = 0; kt < 64; kt++) {
        // ---- Phase 1: S_tile[16 q][32 keys] = Q . K^T ----
        f32x4 sacc[2];
        sacc[0] = f32x4{0.f, 0.f, 0.f, 0.f};
        sacc[1] = f32x4{0.f, 0.f, 0.f, 0.f};
#pragma unroll
        for (int ks = 0; ks < 8; ks++) {
#pragma unroll
            for (int nt = 0; nt < 2; nt++) {
                bf16x8 bfr = *(const bf16x8*)(kbb + (size_t)(kt * 32 + nt * 16 + lm) * D + ks * 32 + lg * 8);
                sacc[nt] = __builtin_amdgcn_mfma_f32_16x16x32_bf16(afrag[ks], bfr, sacc[nt], 0, 0, 0);
            }
        }
        // ---- Phase 2: online softmax (raw-score domain, scale folded into exp2) ----
        float alpha[4];
#pragma unroll
        for (int r = 0; r < 4; r++) {
            float t = fmaxf(sacc[0][r], sacc[1][r]);
            t = fmaxf(t, __shfl_xor(t, 1));
            t = fmaxf(t, __shfl_xor(t, 2));
            t = fmaxf(t, __shfl_xor(t, 4));
            t = fmaxf(t, __shfl_xor(t, 8));
            float mn = fmaxf(m_run[r], t);
            alpha[r] = exp2f((m_run[r] - mn) * SCL);
            m_run[r] = mn;
            float p0 = exp2f((sacc[0][r] - mn) * SCL);
            float p1 = exp2f((sacc[1][r] - mn) * SCL);
            myp[(lg * 4 + r) * 36 + lm]      = p0;
            myp[(lg * 4 + r) * 36 + 16 + lm] = p1;
            float s = p0 + p1;
            s += __shfl_xor(s, 1);
            s += __shfl_xor(s, 2);
            s += __shfl_xor(s, 4);
            s += __shfl_xor(s, 8);
            l_run[r] = l_run[r] * alpha[r] + s;
        }
        // Rescale O by alpha (per C-layout row).
#pragma unroll
        for (int nt = 0; nt < 16; nt++)
#pragma unroll
            for (int r = 0; r < 4; r++) o_acc[nt][r] *= alpha[r];

        asm volatile("s_waitcnt lgkmcnt(0)" ::: "memory");
        // Read P back in A layout: A[m=lm][k=lg*8+j], convert to bf16.
        bf16x8 pfrag;
#pragma unroll
        for (int j = 0; j < 8; j++) pfrag[j] = (bf16_t)myp[lm * 36 + lg * 8 + j];

        // ---- Phase 3: O += P . V  (V^T rows are contiguous in key) ----
#pragma unroll
        for (int nt = 0; nt < 16; nt++) {
            bf16x8 bfr = *(const bf16x8*)(vbb + (size_t)(nt * 16 + lm) * S + kt * 32 + lg * 8);
            o_acc[nt] = __builtin_amdgcn_mfma_f32_16x16x32_bf16(pfrag, bfr, o_acc[nt], 0, 0, 0);
        }
    }

    // ---- Epilogue: out_d += sum over this wave's 16 q rows of O/l ----
#pragma unroll
    for (int nt = 0; nt < 16; nt++) {
        float t = 0.f;
#pragma unroll
        for (int r = 0; r < 4; r++) t += o_acc[nt][r] / l_run[r];
        t += __shfl_xor(t, 16);
        t += __shfl_xor(t, 32);
        if (lane < 16) psum[wave][nt * 16 + lm] = t;
    }
    __syncthreads();
    int tid = threadIdx.x;
    float tot = psum[0][tid] + psum[1][tid] + psum[2][tid] + psum[3][tid];
    partial[(size_t)blockIdx.x * 256 + tid] = tot;
}

// Kernel 4: reduce 32 q-tile partials per (b,d). grid 16 x 256.
__global__ void reduce_kernel(const float* __restrict__ partial, float* __restrict__ out) {
    int b = blockIdx.x, d = threadIdx.x;
    float t = 0.f;
#pragma unroll
    for (int qt = 0; qt < 32; qt++) t += partial[(size_t)(b * 32 + qt) * 256 + d];
    out[b * 256 + d] = t;
}

extern "C" void kernel_launch(void* const* d_in, const int* in_sizes, int n_in,
                              void* d_out, int out_size, void* d_ws, size_t ws_size,
                              hipStream_t stream) {
    const float* x  = (const float*)d_in[0];
    const float* Wq = (const float*)d_in[1];
    const float* bq = (const float*)d_in[2];
    const float* Wk = (const float*)d_in[3];
    const float* bk = (const float*)d_in[4];
    const float* Wv = (const float*)d_in[5];
    const float* bv = (const float*)d_in[6];
    float* out = (float*)d_out;

    char* ws = (char*)d_ws;
    bf16_t* wt      = (bf16_t*)(ws);
    bf16_t* q       = (bf16_t*)(ws + 393216);
    bf16_t* kmat    = (bf16_t*)(ws + 17170432);
    bf16_t* vt      = (bf16_t*)(ws + 33947648);
    float*  partial = (float*) (ws + 50724864);

    wt_kernel<<<dim3(768), dim3(256), 0, stream>>>(Wq, Wk, Wv, wt);
    proj_kernel<<<dim3(512, 3), dim3(256), 0, stream>>>(x, wt, bq, bk, bv, q, kmat, vt);
    attn_kernel<<<dim3(512), dim3(256), 0, stream>>>(q, kmat, vt, partial);
    reduce_kernel<<<dim3(16), dim3(256), 0, stream>>>(partial, out);
}